// Round 1
// baseline (4850.933 us; speedup 1.0000x reference)
//
#include <hip/hip_runtime.h>

// GCN 2-layer + FC on MI355X. Strategy this round: straightforward fp32,
// atomic scatter-add aggregation, self-loops folded into accumulator init,
// layer-2 aggregation done post-GEMM in 64-d (math-equivalent, half traffic).

static constexpr int TPB = 256;

__global__ __launch_bounds__(256) void k_deg_init(float* __restrict__ deg, int n) {
    int i = blockIdx.x * blockDim.x + threadIdx.x;
    if (i < n) deg[i] = 1.0f;   // self-loop contributes 1 to every node's degree
}

__global__ __launch_bounds__(256) void k_deg_count(const int* __restrict__ dst,
                                                   float* __restrict__ deg, int E) {
    int e = blockIdx.x * blockDim.x + threadIdx.x;
    if (e < E) atomicAdd(&deg[dst[e]], 1.0f);
}

__global__ __launch_bounds__(256) void k_rsqrt_(float* __restrict__ deg, int n) {
    int i = blockIdx.x * blockDim.x + threadIdx.x;
    if (i < n) deg[i] = rsqrtf(deg[i]);   // in-place: deg -> dinv
}

// H[n x 128] = X[n x 128] @ W[128 x 128]
__global__ __launch_bounds__(256) void k_gemm1(const float* __restrict__ X,
                                               const float* __restrict__ W,
                                               float* __restrict__ H, int n) {
    int idx = blockIdx.x * blockDim.x + threadIdx.x;
    if (idx >= n * 128) return;
    int r = idx >> 7, c = idx & 127;
    const float* xr = X + (size_t)r * 128;
    float acc = 0.f;
#pragma unroll
    for (int k = 0; k < 128; k += 4) {
        float4 xv = *(const float4*)(xr + k);
        acc = fmaf(xv.x, W[(k + 0) * 128 + c], acc);
        acc = fmaf(xv.y, W[(k + 1) * 128 + c], acc);
        acc = fmaf(xv.z, W[(k + 2) * 128 + c], acc);
        acc = fmaf(xv.w, W[(k + 3) * 128 + c], acc);
    }
    H[idx] = acc;
}

// H2[n x 64] = relu(B[n x 128] + b1) @ W2[128 x 64]   (bias+relu fused on load)
__global__ __launch_bounds__(256) void k_gemm2(const float* __restrict__ B,
                                               const float* __restrict__ W2,
                                               const float* __restrict__ b1,
                                               float* __restrict__ H2, int n) {
    int idx = blockIdx.x * blockDim.x + threadIdx.x;
    if (idx >= n * 64) return;
    int r = idx >> 6, c = idx & 63;
    const float* br = B + (size_t)r * 128;
    float acc = 0.f;
#pragma unroll
    for (int k = 0; k < 128; k += 4) {
        float4 bv = *(const float4*)(br + k);
        float4 bb = *(const float4*)(b1 + k);
        float v0 = fmaxf(bv.x + bb.x, 0.f);
        float v1 = fmaxf(bv.y + bb.y, 0.f);
        float v2 = fmaxf(bv.z + bb.z, 0.f);
        float v3 = fmaxf(bv.w + bb.w, 0.f);
        acc = fmaf(v0, W2[(k + 0) * 64 + c], acc);
        acc = fmaf(v1, W2[(k + 1) * 64 + c], acc);
        acc = fmaf(v2, W2[(k + 2) * 64 + c], acc);
        acc = fmaf(v3, W2[(k + 3) * 64 + c], acc);
    }
    H2[idx] = acc;
}

// OUT[i] = H[i] * dinv[i]^2  (the self-loop message; also initializes the accumulator)
template <int D>
__global__ __launch_bounds__(256) void k_self_init(const float* __restrict__ H,
                                                   const float* __restrict__ dinv,
                                                   float* __restrict__ OUT, int n) {
    int idx = blockIdx.x * blockDim.x + threadIdx.x;
    if (idx >= n * D) return;
    int r = idx / D;
    float di = dinv[r];
    OUT[idx] = H[idx] * (di * di);
}

// OUT[dst] += H[src] * (dinv[src]*dinv[dst]) for all E edges; D floats/row,
// D/4 threads per edge, float4 gather + 4 fp32 global atomics.
template <int D>
__global__ __launch_bounds__(256) void k_scatter(const float* __restrict__ H,
                                                 const float* __restrict__ dinv,
                                                 const int* __restrict__ src,
                                                 const int* __restrict__ dst,
                                                 float* __restrict__ OUT, int E) {
    constexpr int V = D / 4;
    int t = blockIdx.x * blockDim.x + threadIdx.x;
    if (t >= E * V) return;
    int e = t / V;
    int v = t - e * V;
    int s = src[e], d = dst[e];
    float norm = dinv[s] * dinv[d];
    float4 h = *(const float4*)(H + (size_t)s * D + v * 4);
    float* o = OUT + (size_t)d * D + v * 4;
    atomicAdd(o + 0, h.x * norm);
    atomicAdd(o + 1, h.y * norm);
    atomicAdd(o + 2, h.z * norm);
    atomicAdd(o + 3, h.w * norm);
}

// out[n x 10] = relu(C[n x 64] + b2) @ Wfc[64 x 10] + bfc
__global__ __launch_bounds__(256) void k_fc(const float* __restrict__ C,
                                            const float* __restrict__ b2,
                                            const float* __restrict__ Wfc,
                                            const float* __restrict__ bfc,
                                            float* __restrict__ out, int n) {
    int idx = blockIdx.x * blockDim.x + threadIdx.x;
    if (idx >= n * 10) return;
    int r = idx / 10, j = idx - r * 10;
    const float* cr = C + (size_t)r * 64;
    float acc = bfc[j];
#pragma unroll
    for (int c = 0; c < 64; ++c) {
        float v = fmaxf(cr[c] + b2[c], 0.f);
        acc = fmaf(v, Wfc[c * 10 + j], acc);
    }
    out[idx] = acc;
}

static inline int cdiv(long long a, int b) { return (int)((a + b - 1) / b); }

extern "C" void kernel_launch(void* const* d_in, const int* in_sizes, int n_in,
                              void* d_out, int out_size, void* d_ws, size_t ws_size,
                              hipStream_t stream) {
    const float* x   = (const float*)d_in[0];
    const int*   ei  = (const int*)d_in[1];   // int64 request in jax defaults to int32
    const float* W1  = (const float*)d_in[2];
    const float* b1  = (const float*)d_in[3];
    const float* W2  = (const float*)d_in[4];
    const float* b2  = (const float*)d_in[5];
    const float* Wfc = (const float*)d_in[6];
    const float* bfc = (const float*)d_in[7];
    float* out = (float*)d_out;

    const int N = in_sizes[0] / 128;          // 100000
    const int E = in_sizes[1] / 2;            // 1600000
    const int* src = ei;
    const int* dst = ei + E;

    // workspace layout (poisoned each call -> everything re-initialized):
    // [dinv N floats][bufA N*128 floats (H1 then H2)][bufB N*128 floats (agg1 then agg2)]
    char* ws = (char*)d_ws;
    size_t offA = ((size_t)N * 4 + 255) & ~(size_t)255;
    size_t offB = offA + (((size_t)N * 128 * 4 + 255) & ~(size_t)255);
    float* dinv = (float*)ws;
    float* bufA = (float*)(ws + offA);
    float* bufB = (float*)(ws + offB);

    // degrees -> dinv
    k_deg_init<<<cdiv(N, TPB), TPB, 0, stream>>>(dinv, N);
    k_deg_count<<<cdiv(E, TPB), TPB, 0, stream>>>(dst, dinv, E);
    k_rsqrt_<<<cdiv(N, TPB), TPB, 0, stream>>>(dinv, N);

    // layer 1: H1 = x@W1 ; agg1 = A_norm @ H1 (self-loop init + edge scatter)
    k_gemm1<<<cdiv((long long)N * 128, TPB), TPB, 0, stream>>>(x, W1, bufA, N);
    k_self_init<128><<<cdiv((long long)N * 128, TPB), TPB, 0, stream>>>(bufA, dinv, bufB, N);
    k_scatter<128><<<cdiv((long long)E * 32, TPB), TPB, 0, stream>>>(bufA, dinv, src, dst, bufB, E);

    // layer 2: H2 = relu(agg1+b1)@W2 ; agg2 = A_norm @ H2 (64-d aggregation)
    k_gemm2<<<cdiv((long long)N * 64, TPB), TPB, 0, stream>>>(bufB, W2, b1, bufA, N);
    k_self_init<64><<<cdiv((long long)N * 64, TPB), TPB, 0, stream>>>(bufA, dinv, bufB, N);
    k_scatter<64><<<cdiv((long long)E * 16, TPB), TPB, 0, stream>>>(bufA, dinv, src, dst, bufB, E);

    // out = relu(agg2+b2)@Wfc + bfc
    k_fc<<<cdiv((long long)N * 10, TPB), TPB, 0, stream>>>(bufB, b2, Wfc, bfc, out, N);
}

// Round 2
// 1075.237 us; speedup vs baseline: 4.5115x; 4.5115x over previous
//
#include <hip/hip_runtime.h>

// GCN 2-layer + FC. Round 2: CSR-gather aggregation (no float atomics).
// Pipeline: deg(int) -> exclusive scan -> CSR fill -> GEMM1(scale dinv) ->
// gather128 -> GEMM2(bias+relu fused, scale dinv) -> gather64 -> FC.

static constexpr int TPB = 256;

// ---------- CSR build ----------
__global__ __launch_bounds__(256) void k_zero_int(int* __restrict__ p, int n) {
    int i = blockIdx.x * blockDim.x + threadIdx.x;
    if (i < n) p[i] = 0;
}

__global__ __launch_bounds__(256) void k_deg_count(const int* __restrict__ dst,
                                                   int* __restrict__ deg, int E) {
    int e = blockIdx.x * blockDim.x + threadIdx.x;
    if (e < E) atomicAdd(&deg[dst[e]], 1);
}

// Phase A: per-block sums of deg
__global__ __launch_bounds__(256) void k_scan_partial(const int* __restrict__ deg,
                                                      int* __restrict__ bsum, int n) {
    __shared__ int lds[256];
    int i = blockIdx.x * 256 + threadIdx.x;
    lds[threadIdx.x] = (i < n) ? deg[i] : 0;
    __syncthreads();
    for (int off = 128; off > 0; off >>= 1) {
        if (threadIdx.x < off) lds[threadIdx.x] += lds[threadIdx.x + off];
        __syncthreads();
    }
    if (threadIdx.x == 0) bsum[blockIdx.x] = lds[0];
}

// Phase B: single-block exclusive scan of block sums (nb <= 512)
__global__ __launch_bounds__(512) void k_scan_bsums(const int* __restrict__ bsum,
                                                    int* __restrict__ boff, int nb) {
    __shared__ int lds[512];
    int t = threadIdx.x;
    int v = (t < nb) ? bsum[t] : 0;
    lds[t] = v;
    __syncthreads();
    for (int off = 1; off < 512; off <<= 1) {
        int add = (t >= off) ? lds[t - off] : 0;
        __syncthreads();
        lds[t] += add;
        __syncthreads();
    }
    if (t < nb) boff[t] = lds[t] - v;   // exclusive
}

// Phase C: final row_ptr + cursor + dinv
__global__ __launch_bounds__(256) void k_scan_final(const int* __restrict__ deg,
                                                    const int* __restrict__ boff,
                                                    int* __restrict__ row_ptr,
                                                    int* __restrict__ cursor,
                                                    float* __restrict__ dinv, int n) {
    __shared__ int lds[256];
    int i = blockIdx.x * 256 + threadIdx.x;
    int v = (i < n) ? deg[i] : 0;
    lds[threadIdx.x] = v;
    __syncthreads();
    for (int off = 1; off < 256; off <<= 1) {
        int add = (threadIdx.x >= off) ? lds[threadIdx.x - off] : 0;
        __syncthreads();
        lds[threadIdx.x] += add;
        __syncthreads();
    }
    if (i < n) {
        int incl = lds[threadIdx.x];
        int rp = boff[blockIdx.x] + (incl - v);
        row_ptr[i] = rp;
        cursor[i]  = rp;
        dinv[i]    = rsqrtf((float)(v + 1));   // +1 self-loop
        if (i == n - 1) row_ptr[n] = rp + v;
    }
}

__global__ __launch_bounds__(256) void k_fill(const int* __restrict__ src,
                                              const int* __restrict__ dst,
                                              int* __restrict__ cursor,
                                              int* __restrict__ col, int E) {
    int e = blockIdx.x * blockDim.x + threadIdx.x;
    if (e >= E) return;
    int pos = atomicAdd(&cursor[dst[e]], 1);
    col[pos] = src[e];
}

// ---------- GEMMs ----------
// H'[n x 128] = (X[n x 128] @ W[128 x 128]) * dinv[r]
__global__ __launch_bounds__(256) void k_gemm1(const float* __restrict__ X,
                                               const float* __restrict__ W,
                                               const float* __restrict__ dinv,
                                               float* __restrict__ H, int n) {
    int idx = blockIdx.x * blockDim.x + threadIdx.x;
    if (idx >= n * 128) return;
    int r = idx >> 7, c = idx & 127;
    const float* xr = X + (size_t)r * 128;
    float acc = 0.f;
#pragma unroll
    for (int k = 0; k < 128; k += 4) {
        float4 xv = *(const float4*)(xr + k);
        acc = fmaf(xv.x, W[(k + 0) * 128 + c], acc);
        acc = fmaf(xv.y, W[(k + 1) * 128 + c], acc);
        acc = fmaf(xv.z, W[(k + 2) * 128 + c], acc);
        acc = fmaf(xv.w, W[(k + 3) * 128 + c], acc);
    }
    H[idx] = acc * dinv[r];
}

// H2'[n x 64] = (relu(B[n x 128] + b1) @ W2[128 x 64]) * dinv[r]
__global__ __launch_bounds__(256) void k_gemm2(const float* __restrict__ B,
                                               const float* __restrict__ W2,
                                               const float* __restrict__ b1,
                                               const float* __restrict__ dinv,
                                               float* __restrict__ H2, int n) {
    int idx = blockIdx.x * blockDim.x + threadIdx.x;
    if (idx >= n * 64) return;
    int r = idx >> 6, c = idx & 63;
    const float* br = B + (size_t)r * 128;
    float acc = 0.f;
#pragma unroll
    for (int k = 0; k < 128; k += 4) {
        float4 bv = *(const float4*)(br + k);
        float4 bb = *(const float4*)(b1 + k);
        float v0 = fmaxf(bv.x + bb.x, 0.f);
        float v1 = fmaxf(bv.y + bb.y, 0.f);
        float v2 = fmaxf(bv.z + bb.z, 0.f);
        float v3 = fmaxf(bv.w + bb.w, 0.f);
        acc = fmaf(v0, W2[(k + 0) * 64 + c], acc);
        acc = fmaf(v1, W2[(k + 1) * 64 + c], acc);
        acc = fmaf(v2, W2[(k + 2) * 64 + c], acc);
        acc = fmaf(v3, W2[(k + 3) * 64 + c], acc);
    }
    H2[idx] = acc * dinv[r];
}

// ---------- CSR gather: out[d] = (H'[d] + sum_{s in in(d)} H'[s]) * dinv[d] ----------
// One wave per node. VEC floats per lane (VEC*64 == D).
template <int VEC>
__global__ __launch_bounds__(256) void k_gather(const float* __restrict__ Hs,
                                                const float* __restrict__ dinv,
                                                const int* __restrict__ row_ptr,
                                                const int* __restrict__ col,
                                                float* __restrict__ out, int n) {
    int wave = threadIdx.x >> 6;
    int lane = threadIdx.x & 63;
    int node = blockIdx.x * 4 + wave;
    if (node >= n) return;
    int beg = row_ptr[node], end = row_ptr[node + 1];
    int deg = end - beg;

    float acc[VEC];
    const float* hr = Hs + (size_t)node * (VEC * 64) + lane * VEC;
#pragma unroll
    for (int v = 0; v < VEC; ++v) acc[v] = hr[v];   // self term (H' pre-scaled)

    for (int base = 0; base < deg; base += 64) {
        int m = deg - base; if (m > 64) m = 64;
        int cl = (lane < m) ? col[beg + base + lane] : 0;
        for (int j = 0; j < m; ++j) {
            int s = __shfl(cl, j);
            const float* sr = Hs + (size_t)s * (VEC * 64) + lane * VEC;
#pragma unroll
            for (int v = 0; v < VEC; ++v) acc[v] += sr[v];
        }
    }
    float dd = dinv[node];
    float* o = out + (size_t)node * (VEC * 64) + lane * VEC;
#pragma unroll
    for (int v = 0; v < VEC; ++v) o[v] = acc[v] * dd;
}

// ---------- FC ----------
__global__ __launch_bounds__(256) void k_fc(const float* __restrict__ C,
                                            const float* __restrict__ b2,
                                            const float* __restrict__ Wfc,
                                            const float* __restrict__ bfc,
                                            float* __restrict__ out, int n) {
    int idx = blockIdx.x * blockDim.x + threadIdx.x;
    if (idx >= n * 10) return;
    int r = idx / 10, j = idx - r * 10;
    const float* cr = C + (size_t)r * 64;
    float acc = bfc[j];
#pragma unroll
    for (int c = 0; c < 64; ++c) {
        float v = fmaxf(cr[c] + b2[c], 0.f);
        acc = fmaf(v, Wfc[c * 10 + j], acc);
    }
    out[idx] = acc;
}

static inline int cdiv(long long a, int b) { return (int)((a + b - 1) / b); }

extern "C" void kernel_launch(void* const* d_in, const int* in_sizes, int n_in,
                              void* d_out, int out_size, void* d_ws, size_t ws_size,
                              hipStream_t stream) {
    const float* x   = (const float*)d_in[0];
    const int*   ei  = (const int*)d_in[1];
    const float* W1  = (const float*)d_in[2];
    const float* b1  = (const float*)d_in[3];
    const float* W2  = (const float*)d_in[4];
    const float* b2  = (const float*)d_in[5];
    const float* Wfc = (const float*)d_in[6];
    const float* bfc = (const float*)d_in[7];
    float* out = (float*)d_out;

    const int N = in_sizes[0] / 128;   // 100000
    const int E = in_sizes[1] / 2;     // 1600000
    const int* src = ei;
    const int* dst = ei + E;
    const int nb = cdiv(N, 256);       // scan blocks (391)

    // ws layout
    char* ws = (char*)d_ws;
    size_t off = 0;
    auto alloc = [&](size_t bytes) { void* p = ws + off; off = (off + bytes + 255) & ~(size_t)255; return p; };
    float* dinv    = (float*)alloc((size_t)N * 4);
    int*   deg     = (int*)  alloc((size_t)N * 4);
    int*   row_ptr = (int*)  alloc((size_t)(N + 1) * 4);
    int*   cursor  = (int*)  alloc((size_t)N * 4);
    int*   bsum    = (int*)  alloc(512 * 4);
    int*   boff    = (int*)  alloc(512 * 4);
    int*   col     = (int*)  alloc((size_t)E * 4);
    float* bufA    = (float*)alloc((size_t)N * 128 * 4);
    float* bufB    = (float*)alloc((size_t)N * 128 * 4);

    // CSR build
    k_zero_int<<<cdiv(N, TPB), TPB, 0, stream>>>(deg, N);
    k_deg_count<<<cdiv(E, TPB), TPB, 0, stream>>>(dst, deg, E);
    k_scan_partial<<<nb, 256, 0, stream>>>(deg, bsum, N);
    k_scan_bsums<<<1, 512, 0, stream>>>(bsum, boff, nb);
    k_scan_final<<<nb, 256, 0, stream>>>(deg, boff, row_ptr, cursor, dinv, N);
    k_fill<<<cdiv(E, TPB), TPB, 0, stream>>>(src, dst, cursor, col, E);

    // layer 1
    k_gemm1<<<cdiv((long long)N * 128, TPB), TPB, 0, stream>>>(x, W1, dinv, bufA, N);
    k_gather<2><<<cdiv(N, 4), 256, 0, stream>>>(bufA, dinv, row_ptr, col, bufB, N);

    // layer 2 (aggregate post-GEMM in 64-d)
    k_gemm2<<<cdiv((long long)N * 64, TPB), TPB, 0, stream>>>(bufB, W2, b1, dinv, bufA, N);
    k_gather<1><<<cdiv(N, 4), 256, 0, stream>>>(bufA, dinv, row_ptr, col, bufB, N);

    // FC
    k_fc<<<cdiv((long long)N * 10, TPB), TPB, 0, stream>>>(bufB, b2, Wfc, bfc, out, N);
}

// Round 3
// 632.172 us; speedup vs baseline: 7.6734x; 1.7009x over previous
//
#include <hip/hip_runtime.h>

// GCN 2-layer + FC. Round 3: register-blocked fp32 GEMMs (4x8 micro-tile per
// thread), CSR gather with 4x-unrolled in-flight row loads, per-row FC.

static constexpr int TPB = 256;

// ---------- CSR build ----------
__global__ __launch_bounds__(256) void k_zero_int(int* __restrict__ p, int n) {
    int i = blockIdx.x * blockDim.x + threadIdx.x;
    if (i < n) p[i] = 0;
}

__global__ __launch_bounds__(256) void k_deg_count(const int* __restrict__ dst,
                                                   int* __restrict__ deg, int E) {
    int e = blockIdx.x * blockDim.x + threadIdx.x;
    if (e < E) atomicAdd(&deg[dst[e]], 1);
}

__global__ __launch_bounds__(256) void k_scan_partial(const int* __restrict__ deg,
                                                      int* __restrict__ bsum, int n) {
    __shared__ int lds[256];
    int i = blockIdx.x * 256 + threadIdx.x;
    lds[threadIdx.x] = (i < n) ? deg[i] : 0;
    __syncthreads();
    for (int off = 128; off > 0; off >>= 1) {
        if (threadIdx.x < off) lds[threadIdx.x] += lds[threadIdx.x + off];
        __syncthreads();
    }
    if (threadIdx.x == 0) bsum[blockIdx.x] = lds[0];
}

__global__ __launch_bounds__(512) void k_scan_bsums(const int* __restrict__ bsum,
                                                    int* __restrict__ boff, int nb) {
    __shared__ int lds[512];
    int t = threadIdx.x;
    int v = (t < nb) ? bsum[t] : 0;
    lds[t] = v;
    __syncthreads();
    for (int off = 1; off < 512; off <<= 1) {
        int add = (t >= off) ? lds[t - off] : 0;
        __syncthreads();
        lds[t] += add;
        __syncthreads();
    }
    if (t < nb) boff[t] = lds[t] - v;
}

__global__ __launch_bounds__(256) void k_scan_final(const int* __restrict__ deg,
                                                    const int* __restrict__ boff,
                                                    int* __restrict__ row_ptr,
                                                    int* __restrict__ cursor,
                                                    float* __restrict__ dinv, int n) {
    __shared__ int lds[256];
    int i = blockIdx.x * 256 + threadIdx.x;
    int v = (i < n) ? deg[i] : 0;
    lds[threadIdx.x] = v;
    __syncthreads();
    for (int off = 1; off < 256; off <<= 1) {
        int add = (threadIdx.x >= off) ? lds[threadIdx.x - off] : 0;
        __syncthreads();
        lds[threadIdx.x] += add;
        __syncthreads();
    }
    if (i < n) {
        int incl = lds[threadIdx.x];
        int rp = boff[blockIdx.x] + (incl - v);
        row_ptr[i] = rp;
        cursor[i]  = rp;
        dinv[i]    = rsqrtf((float)(v + 1));
        if (i == n - 1) row_ptr[n] = rp + v;
    }
}

__global__ __launch_bounds__(256) void k_fill(const int* __restrict__ src,
                                              const int* __restrict__ dst,
                                              int* __restrict__ cursor,
                                              int* __restrict__ col, int E) {
    int e = blockIdx.x * blockDim.x + threadIdx.x;
    if (e >= E) return;
    int pos = atomicAdd(&cursor[dst[e]], 1);
    col[pos] = src[e];
}

// ---------- GEMM1: H[r][c] = (X @ W)[r][c] * dinv[r]; 100000x128x128 ----------
// Block 256 = 16 tr x 16 tc; thread tile 4 rows x 8 cols.
__global__ __launch_bounds__(256) void k_gemm1(const float* __restrict__ X,
                                               const float* __restrict__ W,
                                               const float* __restrict__ dinv,
                                               float* __restrict__ H, int n) {
    int t = threadIdx.x;
    int tc = t & 15, tr = t >> 4;
    int c0 = tc * 8;
    int r0 = blockIdx.x * 64 + tr * 4;

    const float* xp[4];
#pragma unroll
    for (int i = 0; i < 4; ++i) {
        int r = r0 + i;
        xp[i] = X + (size_t)(r < n ? r : 0) * 128;
    }
    float acc[4][8];
#pragma unroll
    for (int i = 0; i < 4; ++i)
#pragma unroll
        for (int j = 0; j < 8; ++j) acc[i][j] = 0.f;

    for (int k0 = 0; k0 < 128; k0 += 4) {
        float4 xv[4];
#pragma unroll
        for (int i = 0; i < 4; ++i) xv[i] = *(const float4*)(xp[i] + k0);
        float4 w0[4], w1[4];
#pragma unroll
        for (int kk = 0; kk < 4; ++kk) {
            const float* wr = W + (size_t)(k0 + kk) * 128 + c0;
            w0[kk] = *(const float4*)wr;
            w1[kk] = *(const float4*)(wr + 4);
        }
#pragma unroll
        for (int kk = 0; kk < 4; ++kk) {
            const float* wf0 = (const float*)&w0[kk];
            const float* wf1 = (const float*)&w1[kk];
#pragma unroll
            for (int i = 0; i < 4; ++i) {
                float xs = ((const float*)&xv[i])[kk];
#pragma unroll
                for (int j = 0; j < 4; ++j) {
                    acc[i][j]     = fmaf(xs, wf0[j], acc[i][j]);
                    acc[i][j + 4] = fmaf(xs, wf1[j], acc[i][j + 4]);
                }
            }
        }
    }
#pragma unroll
    for (int i = 0; i < 4; ++i) {
        int r = r0 + i;
        if (r >= n) continue;
        float s = dinv[r];
        float4 o0, o1;
        o0.x = acc[i][0] * s; o0.y = acc[i][1] * s; o0.z = acc[i][2] * s; o0.w = acc[i][3] * s;
        o1.x = acc[i][4] * s; o1.y = acc[i][5] * s; o1.z = acc[i][6] * s; o1.w = acc[i][7] * s;
        float* hr = H + (size_t)r * 128 + c0;
        *(float4*)hr = o0;
        *(float4*)(hr + 4) = o1;
    }
}

// ---------- GEMM2: H2[r][c] = (relu(B + b1) @ W2)[r][c] * dinv[r]; Kx64 ----------
// Block 256 = 32 tr x 8 tc; thread tile 4 rows x 8 cols; 128 rows/block.
__global__ __launch_bounds__(256) void k_gemm2(const float* __restrict__ B,
                                               const float* __restrict__ W2,
                                               const float* __restrict__ b1,
                                               const float* __restrict__ dinv,
                                               float* __restrict__ H2, int n) {
    int t = threadIdx.x;
    int tc = t & 7, tr = t >> 3;
    int c0 = tc * 8;
    int r0 = blockIdx.x * 128 + tr * 4;

    const float* xp[4];
#pragma unroll
    for (int i = 0; i < 4; ++i) {
        int r = r0 + i;
        xp[i] = B + (size_t)(r < n ? r : 0) * 128;
    }
    float acc[4][8];
#pragma unroll
    for (int i = 0; i < 4; ++i)
#pragma unroll
        for (int j = 0; j < 8; ++j) acc[i][j] = 0.f;

    for (int k0 = 0; k0 < 128; k0 += 4) {
        float4 bb = *(const float4*)(b1 + k0);
        float4 xv[4];
#pragma unroll
        for (int i = 0; i < 4; ++i) {
            float4 v = *(const float4*)(xp[i] + k0);
            v.x = fmaxf(v.x + bb.x, 0.f);
            v.y = fmaxf(v.y + bb.y, 0.f);
            v.z = fmaxf(v.z + bb.z, 0.f);
            v.w = fmaxf(v.w + bb.w, 0.f);
            xv[i] = v;
        }
        float4 w0[4], w1[4];
#pragma unroll
        for (int kk = 0; kk < 4; ++kk) {
            const float* wr = W2 + (size_t)(k0 + kk) * 64 + c0;
            w0[kk] = *(const float4*)wr;
            w1[kk] = *(const float4*)(wr + 4);
        }
#pragma unroll
        for (int kk = 0; kk < 4; ++kk) {
            const float* wf0 = (const float*)&w0[kk];
            const float* wf1 = (const float*)&w1[kk];
#pragma unroll
            for (int i = 0; i < 4; ++i) {
                float xs = ((const float*)&xv[i])[kk];
#pragma unroll
                for (int j = 0; j < 4; ++j) {
                    acc[i][j]     = fmaf(xs, wf0[j], acc[i][j]);
                    acc[i][j + 4] = fmaf(xs, wf1[j], acc[i][j + 4]);
                }
            }
        }
    }
#pragma unroll
    for (int i = 0; i < 4; ++i) {
        int r = r0 + i;
        if (r >= n) continue;
        float s = dinv[r];
        float4 o0, o1;
        o0.x = acc[i][0] * s; o0.y = acc[i][1] * s; o0.z = acc[i][2] * s; o0.w = acc[i][3] * s;
        o1.x = acc[i][4] * s; o1.y = acc[i][5] * s; o1.z = acc[i][6] * s; o1.w = acc[i][7] * s;
        float* hr = H2 + (size_t)r * 64 + c0;
        *(float4*)hr = o0;
        *(float4*)(hr + 4) = o1;
    }
}

// ---------- CSR gather: out[d] = (H'[d] + sum_{s in in(d)} H'[s]) * dinv[d] ----------
// One wave per node, VEC floats/lane (VEC*64 == D). Inner loop unrolled 4x so
// 4 row-gathers are in flight per s_waitcnt.
template <int VEC>
__global__ __launch_bounds__(256) void k_gather(const float* __restrict__ Hs,
                                                const float* __restrict__ dinv,
                                                const int* __restrict__ row_ptr,
                                                const int* __restrict__ col,
                                                float* __restrict__ out, int n) {
    constexpr int D = VEC * 64;
    int wave = threadIdx.x >> 6;
    int lane = threadIdx.x & 63;
    int node = blockIdx.x * 4 + wave;
    if (node >= n) return;
    int beg = row_ptr[node], end = row_ptr[node + 1];
    int deg = end - beg;

    float acc[VEC];
    const float* hr = Hs + (size_t)node * D + lane * VEC;
#pragma unroll
    for (int v = 0; v < VEC; ++v) acc[v] = hr[v];   // self term (pre-scaled)

    for (int base = 0; base < deg; base += 64) {
        int m = deg - base; if (m > 64) m = 64;
        int cl = (lane < m) ? col[beg + base + lane] : 0;
        int j = 0;
        for (; j + 4 <= m; j += 4) {
            int s0 = __shfl(cl, j + 0);
            int s1 = __shfl(cl, j + 1);
            int s2 = __shfl(cl, j + 2);
            int s3 = __shfl(cl, j + 3);
            const float* p0 = Hs + (size_t)s0 * D + lane * VEC;
            const float* p1 = Hs + (size_t)s1 * D + lane * VEC;
            const float* p2 = Hs + (size_t)s2 * D + lane * VEC;
            const float* p3 = Hs + (size_t)s3 * D + lane * VEC;
            float t0[VEC], t1[VEC], t2[VEC], t3[VEC];
#pragma unroll
            for (int v = 0; v < VEC; ++v) t0[v] = p0[v];
#pragma unroll
            for (int v = 0; v < VEC; ++v) t1[v] = p1[v];
#pragma unroll
            for (int v = 0; v < VEC; ++v) t2[v] = p2[v];
#pragma unroll
            for (int v = 0; v < VEC; ++v) t3[v] = p3[v];
#pragma unroll
            for (int v = 0; v < VEC; ++v)
                acc[v] += (t0[v] + t1[v]) + (t2[v] + t3[v]);
        }
        for (; j < m; ++j) {
            int s = __shfl(cl, j);
            const float* sr = Hs + (size_t)s * D + lane * VEC;
#pragma unroll
            for (int v = 0; v < VEC; ++v) acc[v] += sr[v];
        }
    }
    float dd = dinv[node];
    float* o = out + (size_t)node * D + lane * VEC;
#pragma unroll
    for (int v = 0; v < VEC; ++v) o[v] = acc[v] * dd;
}

// ---------- FC: one thread per row ----------
__global__ __launch_bounds__(256) void k_fc(const float* __restrict__ C,
                                            const float* __restrict__ b2,
                                            const float* __restrict__ Wfc,
                                            const float* __restrict__ bfc,
                                            float* __restrict__ out, int n) {
    int r = blockIdx.x * blockDim.x + threadIdx.x;
    if (r >= n) return;
    const float* cr = C + (size_t)r * 64;
    float acc[10];
#pragma unroll
    for (int j = 0; j < 10; ++j) acc[j] = bfc[j];
#pragma unroll
    for (int c0 = 0; c0 < 64; c0 += 4) {
        float4 v  = *(const float4*)(cr + c0);
        float4 bb = *(const float4*)(b2 + c0);
        float x0 = fmaxf(v.x + bb.x, 0.f);
        float x1 = fmaxf(v.y + bb.y, 0.f);
        float x2 = fmaxf(v.z + bb.z, 0.f);
        float x3 = fmaxf(v.w + bb.w, 0.f);
#pragma unroll
        for (int j = 0; j < 10; ++j) {
            acc[j] = fmaf(x0, Wfc[(c0 + 0) * 10 + j], acc[j]);
            acc[j] = fmaf(x1, Wfc[(c0 + 1) * 10 + j], acc[j]);
            acc[j] = fmaf(x2, Wfc[(c0 + 2) * 10 + j], acc[j]);
            acc[j] = fmaf(x3, Wfc[(c0 + 3) * 10 + j], acc[j]);
        }
    }
    float* o = out + (size_t)r * 10;
#pragma unroll
    for (int j = 0; j < 10; ++j) o[j] = acc[j];
}

static inline int cdiv(long long a, int b) { return (int)((a + b - 1) / b); }

extern "C" void kernel_launch(void* const* d_in, const int* in_sizes, int n_in,
                              void* d_out, int out_size, void* d_ws, size_t ws_size,
                              hipStream_t stream) {
    const float* x   = (const float*)d_in[0];
    const int*   ei  = (const int*)d_in[1];
    const float* W1  = (const float*)d_in[2];
    const float* b1  = (const float*)d_in[3];
    const float* W2  = (const float*)d_in[4];
    const float* b2  = (const float*)d_in[5];
    const float* Wfc = (const float*)d_in[6];
    const float* bfc = (const float*)d_in[7];
    float* out = (float*)d_out;

    const int N = in_sizes[0] / 128;   // 100000
    const int E = in_sizes[1] / 2;     // 1600000
    const int* src = ei;
    const int* dst = ei + E;
    const int nb = cdiv(N, 256);       // 391 <= 512

    char* ws = (char*)d_ws;
    size_t off = 0;
    auto alloc = [&](size_t bytes) { void* p = ws + off; off = (off + bytes + 255) & ~(size_t)255; return p; };
    float* dinv    = (float*)alloc((size_t)N * 4);
    int*   deg     = (int*)  alloc((size_t)N * 4);
    int*   row_ptr = (int*)  alloc((size_t)(N + 1) * 4);
    int*   cursor  = (int*)  alloc((size_t)N * 4);
    int*   bsum    = (int*)  alloc(512 * 4);
    int*   boff    = (int*)  alloc(512 * 4);
    int*   col     = (int*)  alloc((size_t)E * 4);
    float* bufA    = (float*)alloc((size_t)N * 128 * 4);
    float* bufB    = (float*)alloc((size_t)N * 128 * 4);

    // CSR build
    k_zero_int<<<cdiv(N, TPB), TPB, 0, stream>>>(deg, N);
    k_deg_count<<<cdiv(E, TPB), TPB, 0, stream>>>(dst, deg, E);
    k_scan_partial<<<nb, 256, 0, stream>>>(deg, bsum, N);
    k_scan_bsums<<<1, 512, 0, stream>>>(bsum, boff, nb);
    k_scan_final<<<nb, 256, 0, stream>>>(deg, boff, row_ptr, cursor, dinv, N);
    k_fill<<<cdiv(E, TPB), TPB, 0, stream>>>(src, dst, cursor, col, E);

    // layer 1
    k_gemm1<<<cdiv(N, 64), 256, 0, stream>>>(x, W1, dinv, bufA, N);
    k_gather<2><<<cdiv(N, 4), 256, 0, stream>>>(bufA, dinv, row_ptr, col, bufB, N);

    // layer 2 (aggregate post-GEMM in 64-d)
    k_gemm2<<<cdiv(N, 128), 256, 0, stream>>>(bufB, W2, b1, dinv, bufA, N);
    k_gather<1><<<cdiv(N, 4), 256, 0, stream>>>(bufA, dinv, row_ptr, col, bufB, N);

    // FC
    k_fc<<<cdiv(N, 256), 256, 0, stream>>>(bufB, b2, Wfc, bfc, out, N);
}